// Round 8
// baseline (134.589 us; speedup 1.0000x reference)
//
#include <hip/hip_runtime.h>
#include <hip/hip_cooperative_groups.h>
#include <cstdint>

namespace cg = cooperative_groups;

// Problem: B=4, IC=OC=64, H=W=32, K=3, PAD=1
// Outputs: new_x (262144 f32), new_q (262144 f32) concatenated.
//
//   a0 = conv3x3(x,W,pad=1)+bias ; p0 = sigmoid(a0)
//   new_x = 2*(u < p0) - 1,  u = JAX threefry2x32-20, key=(0,42),
//           partitionable counter mode, draw = out0^out1   [verified r2]
//   new_q = 2*new_x*s1*C1   [1st-order Taylor; residual ~1e-4 << 2e-2,
//                            measured r7 absmax 1.18e-4]
//     s1 = p0(1-p0),  C1 = conv3x3(x*q, W)
//
// Round 8: ONE cooperative kernel. Phase 1 digitizes weights into ws
// (4 signed radix-256 digits of round(W*2^31) -> EXACT i8 GEMM path for a0,
// verified r2-r7); threadfence + grid.sync; phase 2 transposes the block's
// 3-row x/q halo into LDS (padded strides: 2 lanes/bank = free) and runs the
// 9-tap MFMA loop with B-frags from LDS, A-frags from L2-resident ws.
// Fragment layouts (16x16 family): A[m=lane&15][k=quad*(K/4)+j],
// B[k=quad*(K/4)+j][n=lane&15], C/D col(n)=lane&15, row(m)=quad*4+reg.

typedef __attribute__((ext_vector_type(4))) int   i32x4;
typedef __attribute__((ext_vector_type(8))) short s16x8;
typedef __attribute__((ext_vector_type(4))) float f32x4;

// ---- ws byte offsets ----
static constexpr int OFF_WD = 0;        // i8  [dig4][tap9][oc64][ic64] 147,456 B
static constexpr int OFF_WB = 147456;   // bf16[tap9][oc64][ic64]        73,728 B
// total ws use: 221,184 B

// LDS plane strides (bytes/ushorts per pixel), padded for conflict-free b128
static constexpr int X8_STRIDE = 80;    // bytes per pixel (64 + 16 pad)
static constexpr int XQ_STRIDE = 72;    // ushorts per pixel (64 + 8 pad = 144 B)

__device__ __forceinline__ uint32_t rotl32(uint32_t v, int n) {
  return (v << n) | (v >> (32 - n));
}

__device__ __forceinline__ unsigned short f2bf(float f) {
  uint32_t u = __float_as_uint(f);
  uint32_t r = (u + 0x7FFFu + ((u >> 16) & 1u)) >> 16;   // RNE
  return (unsigned short)r;
}

// JAX threefry2x32-20, key=(0,42), partitionable: counter (0,j), draw=out0^out1
__device__ __forceinline__ float threefry_u(uint32_t j) {
  uint32_t x0 = 0u, x1 = j;
  const uint32_t ks1 = 42u, ks2 = 0x1BD11BDAu ^ 42u;
  x0 += 0u; x1 += ks1;
#define QR(rot) { x0 += x1; x1 = rotl32(x1, rot); x1 ^= x0; }
  QR(13) QR(15) QR(26) QR(6)
  x0 += ks1; x1 += ks2 + 1u;
  QR(17) QR(29) QR(16) QR(24)
  x0 += ks2; x1 += 0u + 2u;
  QR(13) QR(15) QR(26) QR(6)
  x0 += 0u; x1 += ks1 + 3u;
  QR(17) QR(29) QR(16) QR(24)
  x0 += ks1; x1 += ks2 + 4u;
  QR(13) QR(15) QR(26) QR(6)
  x0 += ks2; x1 += 0u + 5u;
#undef QR
  uint32_t bits = x0 ^ x1;
  return __uint_as_float((bits >> 9) | 0x3F800000u) - 1.0f;
}

// ---------------- fused kernel: 128 blocks (b*32+h) x 512 threads -------------------
__global__ __launch_bounds__(512) void fused_kernel(
    const float* __restrict__ x, const float* __restrict__ q,
    const float* __restrict__ weight, const float* __restrict__ bias,
    char* __restrict__ ws, float* __restrict__ out) {
  __shared__ char           x8s[3 * 34 * X8_STRIDE];   // 8,160 B
  __shared__ unsigned short xqs[3 * 34 * XQ_STRIDE];   // 14,688 B

  const int blk = blockIdx.x;
  const int tid = threadIdx.x;
  const int b = blk >> 5;
  const int h = blk & 31;

  // ---- phase 0: zero LDS (covers borders + padding) ----
  {
    int* z1 = (int*)x8s;
#pragma unroll
    for (int i = tid; i < 3 * 34 * X8_STRIDE / 4; i += 512) z1[i] = 0;
    int* z2 = (int*)xqs;
#pragma unroll
    for (int i = tid; i < 3 * 34 * XQ_STRIDE / 2; i += 512) z2[i] = 0;
  }

  // ---- phase 1: weight digitization (288 items/block, coalesced ws writes) ----
  if (tid < 288) {
    const int k  = blk * 288 + tid;        // k = tap*4096 + oc*64 + ic
    const int ic = k & 63;
    const int t  = k >> 6;
    const int oc  = t & 63;
    const int tap = t >> 6;
    const int kh = tap / 3, kw = tap % 3;
    float Wv = weight[((oc * 64 + ic) * 3 + kh) * 3 + kw];
    long long wi = llrint((double)Wv * 2147483648.0);   // round(W*2^31), |wi|<2^28
    char* wdp = ws + OFF_WD;
#pragma unroll
    for (int dig = 0; dig < 4; ++dig) {
      signed char d = (signed char)(wi & 0xFF);          // balanced low byte
      wdp[dig * 36864 + k] = d;
      wi = (wi - (long long)d) >> 8;
    }
    ((unsigned short*)(ws + OFF_WB))[k] = f2bf(Wv);
  }

  __syncthreads();   // LDS zeros complete before interior fill

  // ---- phase 2a: halo transpose into LDS ----
  {
    const int ic = tid & 63;
    const int rw = tid >> 6;               // 0..7; use 0..5
    if (rw < 6) {
      const int r  = rw >> 1;              // halo row 0..2  (global h-1+r)
      const int wh = (rw & 1) * 16;        // w chunk 0 or 16
      const int hg = h - 1 + r;
      if (hg >= 0 && hg < 32) {
        const int src = ((b * 64 + ic) * 32 + hg) * 32 + wh;
        float4 xa = *(const float4*)(x + src);
        float4 xb = *(const float4*)(x + src + 4);
        float4 xc = *(const float4*)(x + src + 8);
        float4 xd = *(const float4*)(x + src + 12);
        float4 qa = *(const float4*)(q + src);
        float4 qb = *(const float4*)(q + src + 4);
        float4 qc = *(const float4*)(q + src + 8);
        float4 qd = *(const float4*)(q + src + 12);
        float xv[16] = {xa.x, xa.y, xa.z, xa.w, xb.x, xb.y, xb.z, xb.w,
                        xc.x, xc.y, xc.z, xc.w, xd.x, xd.y, xd.z, xd.w};
        float qv[16] = {qa.x, qa.y, qa.z, qa.w, qb.x, qb.y, qb.z, qb.w,
                        qc.x, qc.y, qc.z, qc.w, qd.x, qd.y, qd.z, qd.w};
#pragma unroll
        for (int j = 0; j < 16; ++j) {
          const int wp = wh + j + 1;       // interior 1..32
          x8s[(r * 34 + wp) * X8_STRIDE + ic] = (char)(int)xv[j];
          xqs[(r * 34 + wp) * XQ_STRIDE + ic] = f2bf(xv[j] * qv[j]);
        }
      }
    }
  }

  __threadfence();        // wd/wb device-visible before the grid barrier
  cg::this_grid().sync(); // also orders LDS writes for the block

  // ---- phase 2b: 9-tap MFMA loop ----
  const char* wdp           = ws + OFF_WD;
  const unsigned short* wbp = (const unsigned short*)(ws + OFF_WB);

  const int ww     = tid >> 6;       // 0..7
  const int octile = ww & 3;
  const int nt     = ww >> 2;
  const int lane   = tid & 63;
  const int quad   = lane >> 4;
  const int l16    = lane & 15;

  i32x4 accI[4];
#pragma unroll
  for (int d = 0; d < 4; ++d) accI[d] = (i32x4){0, 0, 0, 0};
  f32x4 aC1 = {0.f, 0.f, 0.f, 0.f};

  const int aoff_i8 = (octile * 16 + l16) * 64 + quad * 16;   // bytes
  const int aoff_bf = (octile * 16 + l16) * 64 + quad * 8;    // ushort elems
  const int pxb = nt * 16 + l16;

#pragma unroll
  for (int kh = 0; kh < 3; ++kh) {
#pragma unroll
    for (int kw = 0; kw < 3; ++kw) {
      const int tap = kh * 3 + kw;
      i32x4 aI[4];
#pragma unroll
      for (int d = 0; d < 4; ++d)
        aI[d] = *(const i32x4*)(wdp + d * 36864 + tap * 4096 + aoff_i8);
      s16x8 aW0 = *(const s16x8*)(wbp + tap * 4096 + aoff_bf);
      s16x8 aW1 = *(const s16x8*)(wbp + tap * 4096 + aoff_bf + 32);
      const int px = kh * 34 + pxb + kw;
      i32x4 bI  = *(const i32x4*)&x8s[px * X8_STRIDE + quad * 16];
      const unsigned short* xp = &xqs[px * XQ_STRIDE + quad * 8];
      s16x8 bX0 = *(const s16x8*)xp;
      s16x8 bX1 = *(const s16x8*)(xp + 32);
#pragma unroll
      for (int d = 0; d < 4; ++d)
        accI[d] = __builtin_amdgcn_mfma_i32_16x16x64_i8(aI[d], bI, accI[d], 0, 0, 0);
      aC1 = __builtin_amdgcn_mfma_f32_16x16x32_bf16(aW0, bX0, aC1, 0, 0, 0);
      aC1 = __builtin_amdgcn_mfma_f32_16x16x32_bf16(aW1, bX1, aC1, 0, 0, 0);
    }
  }

  // ---- epilogue: C/D col(n=px)=l16, row(m=oc)=quad*4+r ----
  const int w = nt * 16 + l16;
#pragma unroll
  for (int r = 0; r < 4; ++r) {
    const int ocr = octile * 16 + quad * 4 + r;
    double a0 = (((double)accI[3][r] * 256.0 + (double)accI[2][r]) * 256.0 +
                 (double)accI[1][r]) * 256.0 + (double)accI[0][r];
    a0 = a0 * (1.0 / 2147483648.0) + (double)bias[ocr];
    double p0d = 1.0 / (1.0 + exp(-a0));
    const int o = ((b * 64 + ocr) * 32 + h) * 32 + w;
    float su = threefry_u((uint32_t)o);
    float nx = ((double)su < p0d) ? 1.0f : -1.0f;
    float p0 = (float)p0d;
    float s1 = p0 * (1.0f - p0);
    float dq = 2.0f * nx * s1 * aC1[r];
    out[o] = nx;
    out[262144 + o] = dq;
  }
}

extern "C" void kernel_launch(void* const* d_in, const int* in_sizes, int n_in,
                              void* d_out, int out_size, void* d_ws, size_t ws_size,
                              hipStream_t stream) {
  const float* x      = (const float*)d_in[0];
  const float* q      = (const float*)d_in[1];
  const float* weight = (const float*)d_in[2];
  const float* bias   = (const float*)d_in[3];
  float* out = (float*)d_out;
  char* ws   = (char*)d_ws;

  void* args[] = {(void*)&x, (void*)&q, (void*)&weight, (void*)&bias,
                  (void*)&ws, (void*)&out};
  hipLaunchCooperativeKernel(reinterpret_cast<void*>(fused_kernel),
                             dim3(128), dim3(512), args, 0, stream);
}

// Round 9
// 76.722 us; speedup vs baseline: 1.7543x; 1.7543x over previous
//
#include <hip/hip_runtime.h>
#include <cstdint>

// Problem: B=4, IC=OC=64, H=W=32, K=3, PAD=1
// Outputs: new_x (262144 f32), new_q (262144 f32) concatenated.
//
//   a0 = conv3x3(x,W,pad=1)+bias ; p0 = sigmoid(a0)
//   new_x = 2*(u < p0) - 1,  u = JAX threefry2x32-20, key=(0,42),
//           partitionable counter mode, draw = out0^out1   [verified r2]
//   new_q = 2*new_x*s1*C1   [1st-order Taylor; residual ~1.2e-4 << 2e-2,
//                            measured r7]
//     s1 = p0(1-p0),  C1 = conv3x3(x*q, W)
//
// Round 9: r7 two-kernel structure (best: 72.5us; r8 coop fusion regressed to
// 134us — grid.sync costs ~50us on 8 XCDs, recorded).
//  - main: 512 blocks; block pairs duplicate the MFMA tile (idle matrix pipe)
//    but split the 4-row epilogue 2/2 -> 2 waves/SIMD TLP + half the serial
//    f64/threefry tail per wave.
//  - epilogue: f32 expf fast path; f64 sigmoid fallback only when
//    |u - p0_f32| < 1e-5 (provably decision-identical: a0 exact to 1.3e-7).
// a0 path EXACT as r2-r8: W as 4 signed radix-256 digits of round(W*2^31),
// x as i8, mfma_i32_16x16x64_i8 (i32 exact), f64 reconstruction.
// Fragment layouts (16x16 family): A[m=lane&15][k=quad*(K/4)+j],
// B[k=quad*(K/4)+j][n=lane&15], C/D col(n)=lane&15, row(m)=quad*4+reg.

typedef __attribute__((ext_vector_type(4))) int   i32x4;
typedef __attribute__((ext_vector_type(8))) short s16x8;
typedef __attribute__((ext_vector_type(4))) float f32x4;

// ---- ws byte offsets ----
static constexpr int OFF_X8   = 0;          // i8  [b][34][34][64]   295,936 B
static constexpr int OFF_XQH  = 295936;     // bf16[b][34][34][64]   591,872 B
static constexpr int OFF_WD   = 887808;     // i8  [dig4][tap9][oc64][ic64] 147,456 B
static constexpr int OFF_WB   = 1035264;    // bf16[tap9][oc64][ic64] 73,728 B
// total 1,108,992 B

__device__ __forceinline__ uint32_t rotl32(uint32_t v, int n) {
  return (v << n) | (v >> (32 - n));
}

__device__ __forceinline__ unsigned short f2bf(float f) {
  uint32_t u = __float_as_uint(f);
  uint32_t r = (u + 0x7FFFu + ((u >> 16) & 1u)) >> 16;   // RNE
  return (unsigned short)r;
}

// JAX threefry2x32-20, key=(0,42), partitionable: counter (0,j), draw=out0^out1
__device__ __forceinline__ float threefry_u(uint32_t j) {
  uint32_t x0 = 0u, x1 = j;
  const uint32_t ks1 = 42u, ks2 = 0x1BD11BDAu ^ 42u;
  x0 += 0u; x1 += ks1;
#define QR(rot) { x0 += x1; x1 = rotl32(x1, rot); x1 ^= x0; }
  QR(13) QR(15) QR(26) QR(6)
  x0 += ks1; x1 += ks2 + 1u;
  QR(17) QR(29) QR(16) QR(24)
  x0 += ks2; x1 += 0u + 2u;
  QR(13) QR(15) QR(26) QR(6)
  x0 += 0u; x1 += ks1 + 3u;
  QR(17) QR(29) QR(16) QR(24)
  x0 += ks1; x1 += ks2 + 4u;
  QR(13) QR(15) QR(26) QR(6)
  x0 += ks2; x1 += 0u + 5u;
#undef QR
  uint32_t bits = x0 ^ x1;
  return __uint_as_float((bits >> 9) | 0x3F800000u) - 1.0f;
}

// ---------------- prep (unchanged from r7) ------------------------------------------
__global__ __launch_bounds__(256) void prep_kernel(
    const float* __restrict__ x, const float* __restrict__ q,
    const float* __restrict__ weight, char* __restrict__ ws) {
  const int blk = blockIdx.x;
  const int tid = threadIdx.x;

  if (blk < 128) {
    const int b = blk >> 5;
    const int h = blk & 31;
    __shared__ char           x8s[2048];   // [w][ic]
    __shared__ unsigned short xqs[2048];
    const int ic = tid >> 2;
    const int w0 = (tid & 3) * 8;
    const int src = ((b * 64 + ic) * 32 + h) * 32 + w0;
    float4 xa = *(const float4*)(x + src);
    float4 xb = *(const float4*)(x + src + 4);
    float4 qa = *(const float4*)(q + src);
    float4 qb = *(const float4*)(q + src + 4);
    float xv[8] = {xa.x, xa.y, xa.z, xa.w, xb.x, xb.y, xb.z, xb.w};
    float qv[8] = {qa.x, qa.y, qa.z, qa.w, qb.x, qb.y, qb.z, qb.w};
#pragma unroll
    for (int j = 0; j < 8; ++j) {
      int a = (w0 + j) * 64 + ic;
      x8s[a] = (char)(int)xv[j];
      xqs[a] = f2bf(xv[j] * qv[j]);
    }
    __syncthreads();
    const int rowel = ((b * 34 + h + 1) * 34 + 1) * 64;
    ((uint2*)(ws + OFF_X8 + rowel))[tid]      = ((const uint2*)x8s)[tid];
    ((uint4*)(ws + OFF_XQH + rowel * 2))[tid] = ((const uint4*)xqs)[tid];
  } else if (blk < 132) {
    const int b = blk - 128;
    for (int k = tid; k < 8448; k += 256) {
      int cell = k >> 6;
      int ic = k & 63;
      int hp, wp;
      if (cell < 34)       { hp = 0;          wp = cell; }
      else if (cell < 68)  { hp = 33;         wp = cell - 34; }
      else if (cell < 100) { hp = cell - 67;  wp = 0; }
      else                 { hp = cell - 99;  wp = 33; }
      int a = ((b * 34 + hp) * 34 + wp) * 64 + ic;
      ((char*)(ws + OFF_X8))[a] = 0;
      ((unsigned short*)(ws + OFF_XQH))[a] = 0;
    }
  } else {
    int k  = (blk - 132) * 256 + tid;      // < 36864, k = tap*4096 + oc*64 + ic
    int ic = k & 63;
    int t  = k >> 6;
    int oc  = t & 63;
    int tap = t >> 6;
    int kh = tap / 3, kw = tap % 3;
    float Wv = weight[((oc * 64 + ic) * 3 + kh) * 3 + kw];
    long long wi = llrint((double)Wv * 2147483648.0);   // round(W*2^31), |wi|<2^28
    char* wd = ws + OFF_WD;
#pragma unroll
    for (int dig = 0; dig < 4; ++dig) {
      signed char d = (signed char)(wi & 0xFF);          // balanced low byte
      wd[dig * 36864 + k] = d;
      wi = (wi - (long long)d) >> 8;
    }
    ((unsigned short*)(ws + OFF_WB))[k]  = f2bf(Wv);
  }
}

// ---------------- main: duplicated-tile MFMA + split fast epilogue ------------------
// grid 512 = (((b*32+h)*2)+nt)*2 + rhalf ; block 256 = 4 waves (octiles)
__global__ __launch_bounds__(256) void main_kernel(
    const char* __restrict__ ws, const float* __restrict__ bias,
    float* __restrict__ out) {
  const char* x8            = ws + OFF_X8;
  const unsigned short* xqh = (const unsigned short*)(ws + OFF_XQH);
  const char* wd            = ws + OFF_WD;
  const unsigned short* wb  = (const unsigned short*)(ws + OFF_WB);

  const int rhalf = blockIdx.x & 1;        // epilogue rows 0-1 or 2-3
  const int nt    = (blockIdx.x >> 1) & 1;
  const int h     = (blockIdx.x >> 2) & 31;
  const int b     = blockIdx.x >> 7;

  const int octile = threadIdx.x >> 6;
  const int lane   = threadIdx.x & 63;
  const int quad   = lane >> 4;
  const int l16    = lane & 15;

  i32x4 accI[4];
#pragma unroll
  for (int d = 0; d < 4; ++d) accI[d] = (i32x4){0, 0, 0, 0};
  f32x4 aC1 = {0.f, 0.f, 0.f, 0.f};

  const int aoff_i8 = (octile * 16 + l16) * 64 + quad * 16;   // bytes
  const int aoff_bf = (octile * 16 + l16) * 64 + quad * 8;    // ushort elems

#pragma unroll
  for (int kh = 0; kh < 3; ++kh) {
#pragma unroll
    for (int kw = 0; kw < 3; ++kw) {
      const int tap = kh * 3 + kw;
      i32x4 aI[4];
#pragma unroll
      for (int d = 0; d < 4; ++d)
        aI[d] = *(const i32x4*)(wd + d * 36864 + tap * 4096 + aoff_i8);
      s16x8 aW0 = *(const s16x8*)(wb + tap * 4096 + aoff_bf);
      s16x8 aW1 = *(const s16x8*)(wb + tap * 4096 + aoff_bf + 32);
      const int pix = ((b * 34 + h + kh) * 34 + (nt * 16 + l16 + kw)) * 64;
      i32x4 bI  = *(const i32x4*)(x8 + pix + quad * 16);
      s16x8 bX0 = *(const s16x8*)(xqh + pix + quad * 8);
      s16x8 bX1 = *(const s16x8*)(xqh + pix + 32 + quad * 8);
#pragma unroll
      for (int d = 0; d < 4; ++d)
        accI[d] = __builtin_amdgcn_mfma_i32_16x16x64_i8(aI[d], bI, accI[d], 0, 0, 0);
      aC1 = __builtin_amdgcn_mfma_f32_16x16x32_bf16(aW0, bX0, aC1, 0, 0, 0);
      aC1 = __builtin_amdgcn_mfma_f32_16x16x32_bf16(aW1, bX1, aC1, 0, 0, 0);
    }
  }

  // ---- epilogue (2 rows): C/D col(n=px)=l16, row(m=oc)=quad*4+r ----
  const int w = nt * 16 + l16;
#pragma unroll
  for (int rr = 0; rr < 2; ++rr) {
    const int r = rhalf * 2 + rr;
    const int ocr = octile * 16 + quad * 4 + r;
    double a0d = (((double)accI[3][r] * 256.0 + (double)accI[2][r]) * 256.0 +
                  (double)accI[1][r]) * 256.0 + (double)accI[0][r];
    a0d = a0d * (1.0 / 2147483648.0) + (double)bias[ocr];
    const int o = ((b * 64 + ocr) * 32 + h) * 32 + w;
    float su = threefry_u((uint32_t)o);
    // fast f32 sigmoid; a0 is exact to ~1.3e-7, f32 path error ~1e-7
    float p0 = 1.0f / (1.0f + expf(-(float)a0d));
    float diff = su - p0;
    float nx;
    if (fabsf(diff) >= 1e-5f) {
      nx = (diff < 0.0f) ? 1.0f : -1.0f;
    } else {
      // rare (~5 lanes per launch): exact f64 decision (r2-r8 proven path)
      double p0d = 1.0 / (1.0 + exp(-a0d));
      nx = ((double)su < p0d) ? 1.0f : -1.0f;
    }
    float s1 = p0 * (1.0f - p0);
    float dq = 2.0f * nx * s1 * aC1[r];
    out[o] = nx;
    out[262144 + o] = dq;
  }
}

extern "C" void kernel_launch(void* const* d_in, const int* in_sizes, int n_in,
                              void* d_out, int out_size, void* d_ws, size_t ws_size,
                              hipStream_t stream) {
  const float* x      = (const float*)d_in[0];
  const float* q      = (const float*)d_in[1];
  const float* weight = (const float*)d_in[2];
  const float* bias   = (const float*)d_in[3];
  float* out = (float*)d_out;
  char* ws   = (char*)d_ws;

  // prep: 128 row blocks + 4 border blocks + 144 weight blocks = 276
  prep_kernel<<<276, 256, 0, stream>>>(x, q, weight, ws);
  // main: 512 blocks (tile-pairs splitting the epilogue), 256 threads
  main_kernel<<<512, 256, 0, stream>>>(ws, bias, out);
}

// Round 10
// 71.157 us; speedup vs baseline: 1.8914x; 1.0782x over previous
//
#include <hip/hip_runtime.h>
#include <cstdint>

// Problem: B=4, IC=OC=64, H=W=32, K=3, PAD=1
// Outputs: new_x (262144 f32), new_q (262144 f32) concatenated.
//
//   a0 = conv3x3(x,W,pad=1)+bias ; p0 = sigmoid(a0)
//   new_x = 2*(u < p0) - 1,  u = JAX threefry2x32-20, key=(0,42),
//           partitionable counter mode, draw = out0^out1   [verified r2]
//   new_q = 2*new_x*s1*C1   [1st-order Taylor; residual ~1.2e-4 << 2e-2, r7]
//     s1 = p0(1-p0),  C1 = conv3x3(x*q, W)
//
// Round 10: r7 structure (best, 72.5us; r6 K-split/r8 coop-fusion/r9 tile-dup
// all regressed) + ILP fix: main showed only 48-56 VGPRs at 1 wave/SIMD ->
// loads serially exposed. __launch_bounds__(256,1) raises the VGPR cap
// (occupancy is free at 1024 waves/1024 SIMDs) and all 27 B-fragment loads
// are explicitly preloaded so the B stream pipelines; compiler can hoist
// A-loads with the headroom.
// a0 path EXACT (r2-r9): W as 4 signed radix-256 digits of round(W*2^31),
// x as i8, mfma_i32_16x16x64_i8 (i32 exact), f64 reconstruction + f64 exp.
// Fragment layouts (16x16 family): A[m=lane&15][k=quad*(K/4)+j],
// B[k=quad*(K/4)+j][n=lane&15], C/D col(n)=lane&15, row(m)=quad*4+reg.

typedef __attribute__((ext_vector_type(4))) int   i32x4;
typedef __attribute__((ext_vector_type(8))) short s16x8;
typedef __attribute__((ext_vector_type(4))) float f32x4;

// ---- ws byte offsets ----
static constexpr int OFF_X8   = 0;          // i8  [b][34][34][64]   295,936 B
static constexpr int OFF_XQH  = 295936;     // bf16[b][34][34][64]   591,872 B
static constexpr int OFF_WD   = 887808;     // i8  [dig4][tap9][oc64][ic64] 147,456 B
static constexpr int OFF_WB   = 1035264;    // bf16[tap9][oc64][ic64] 73,728 B
// total 1,108,992 B

__device__ __forceinline__ uint32_t rotl32(uint32_t v, int n) {
  return (v << n) | (v >> (32 - n));
}

__device__ __forceinline__ unsigned short f2bf(float f) {
  uint32_t u = __float_as_uint(f);
  uint32_t r = (u + 0x7FFFu + ((u >> 16) & 1u)) >> 16;   // RNE
  return (unsigned short)r;
}

// JAX threefry2x32-20, key=(0,42), partitionable: counter (0,j), draw=out0^out1
__device__ __forceinline__ float threefry_u(uint32_t j) {
  uint32_t x0 = 0u, x1 = j;
  const uint32_t ks1 = 42u, ks2 = 0x1BD11BDAu ^ 42u;
  x0 += 0u; x1 += ks1;
#define QR(rot) { x0 += x1; x1 = rotl32(x1, rot); x1 ^= x0; }
  QR(13) QR(15) QR(26) QR(6)
  x0 += ks1; x1 += ks2 + 1u;
  QR(17) QR(29) QR(16) QR(24)
  x0 += ks2; x1 += 0u + 2u;
  QR(13) QR(15) QR(26) QR(6)
  x0 += 0u; x1 += ks1 + 3u;
  QR(17) QR(29) QR(16) QR(24)
  x0 += ks1; x1 += ks2 + 4u;
  QR(13) QR(15) QR(26) QR(6)
  x0 += ks2; x1 += 0u + 5u;
#undef QR
  uint32_t bits = x0 ^ x1;
  return __uint_as_float((bits >> 9) | 0x3F800000u) - 1.0f;
}

// ---------------- prep (unchanged from r7) ------------------------------------------
__global__ __launch_bounds__(256) void prep_kernel(
    const float* __restrict__ x, const float* __restrict__ q,
    const float* __restrict__ weight, char* __restrict__ ws) {
  const int blk = blockIdx.x;
  const int tid = threadIdx.x;

  if (blk < 128) {
    const int b = blk >> 5;
    const int h = blk & 31;
    __shared__ char           x8s[2048];   // [w][ic]
    __shared__ unsigned short xqs[2048];
    const int ic = tid >> 2;
    const int w0 = (tid & 3) * 8;
    const int src = ((b * 64 + ic) * 32 + h) * 32 + w0;
    float4 xa = *(const float4*)(x + src);
    float4 xb = *(const float4*)(x + src + 4);
    float4 qa = *(const float4*)(q + src);
    float4 qb = *(const float4*)(q + src + 4);
    float xv[8] = {xa.x, xa.y, xa.z, xa.w, xb.x, xb.y, xb.z, xb.w};
    float qv[8] = {qa.x, qa.y, qa.z, qa.w, qb.x, qb.y, qb.z, qb.w};
#pragma unroll
    for (int j = 0; j < 8; ++j) {
      int a = (w0 + j) * 64 + ic;
      x8s[a] = (char)(int)xv[j];
      xqs[a] = f2bf(xv[j] * qv[j]);
    }
    __syncthreads();
    const int rowel = ((b * 34 + h + 1) * 34 + 1) * 64;
    ((uint2*)(ws + OFF_X8 + rowel))[tid]      = ((const uint2*)x8s)[tid];
    ((uint4*)(ws + OFF_XQH + rowel * 2))[tid] = ((const uint4*)xqs)[tid];
  } else if (blk < 132) {
    const int b = blk - 128;
    for (int k = tid; k < 8448; k += 256) {
      int cell = k >> 6;
      int ic = k & 63;
      int hp, wp;
      if (cell < 34)       { hp = 0;          wp = cell; }
      else if (cell < 68)  { hp = 33;         wp = cell - 34; }
      else if (cell < 100) { hp = cell - 67;  wp = 0; }
      else                 { hp = cell - 99;  wp = 33; }
      int a = ((b * 34 + hp) * 34 + wp) * 64 + ic;
      ((char*)(ws + OFF_X8))[a] = 0;
      ((unsigned short*)(ws + OFF_XQH))[a] = 0;
    }
  } else {
    int k  = (blk - 132) * 256 + tid;      // < 36864, k = tap*4096 + oc*64 + ic
    int ic = k & 63;
    int t  = k >> 6;
    int oc  = t & 63;
    int tap = t >> 6;
    int kh = tap / 3, kw = tap % 3;
    float Wv = weight[((oc * 64 + ic) * 3 + kh) * 3 + kw];
    long long wi = llrint((double)Wv * 2147483648.0);   // round(W*2^31), |wi|<2^28
    char* wd = ws + OFF_WD;
#pragma unroll
    for (int dig = 0; dig < 4; ++dig) {
      signed char d = (signed char)(wi & 0xFF);          // balanced low byte
      wd[dig * 36864 + k] = d;
      wi = (wi - (long long)d) >> 8;
    }
    ((unsigned short*)(ws + OFF_WB))[k]  = f2bf(Wv);
  }
}

// ---------------- main: MFMA convs, B-stream preloaded, f64 epilogue ----------------
// grid 256 = (b*32 + h)*2 + nt ; block 256 = 4 waves, wave = oc-tile (16 oc)
// __launch_bounds__(256,1): 1 wave/EU min -> VGPR cap ~512; grid gives
// 1 wave/SIMD anyway, so registers are free — spend them on load ILP.
__global__ __launch_bounds__(256, 1) void main_kernel(
    const char* __restrict__ ws, const float* __restrict__ bias,
    float* __restrict__ out) {
  const char* x8            = ws + OFF_X8;
  const unsigned short* xqh = (const unsigned short*)(ws + OFF_XQH);
  const char* wd            = ws + OFF_WD;
  const unsigned short* wb  = (const unsigned short*)(ws + OFF_WB);

  const int b  = blockIdx.x >> 6;
  const int h  = (blockIdx.x >> 1) & 31;
  const int nt = blockIdx.x & 1;

  const int octile = threadIdx.x >> 6;
  const int lane   = threadIdx.x & 63;
  const int quad   = lane >> 4;
  const int l16    = lane & 15;

  // ---- preload ALL 9 B-fragment sets (27 b128 loads issued back-to-back) ----
  i32x4 bI[9];
  s16x8 bX[9][2];
#pragma unroll
  for (int kh = 0; kh < 3; ++kh) {
#pragma unroll
    for (int kw = 0; kw < 3; ++kw) {
      const int t = kh * 3 + kw;
      const int pix = ((b * 34 + h + kh) * 34 + (nt * 16 + l16 + kw)) * 64;
      bI[t]    = *(const i32x4*)(x8 + pix + quad * 16);
      bX[t][0] = *(const s16x8*)(xqh + pix + quad * 8);
      bX[t][1] = *(const s16x8*)(xqh + pix + 32 + quad * 8);
    }
  }

  i32x4 accI[4];
#pragma unroll
  for (int d = 0; d < 4; ++d) accI[d] = (i32x4){0, 0, 0, 0};
  f32x4 aC1 = {0.f, 0.f, 0.f, 0.f};

  const int aoff_i8 = (octile * 16 + l16) * 64 + quad * 16;   // bytes
  const int aoff_bf = (octile * 16 + l16) * 64 + quad * 8;    // ushort elems

#pragma unroll
  for (int tap = 0; tap < 9; ++tap) {
    i32x4 aI[4];
#pragma unroll
    for (int d = 0; d < 4; ++d)
      aI[d] = *(const i32x4*)(wd + d * 36864 + tap * 4096 + aoff_i8);
    s16x8 aW0 = *(const s16x8*)(wb + tap * 4096 + aoff_bf);
    s16x8 aW1 = *(const s16x8*)(wb + tap * 4096 + aoff_bf + 32);
#pragma unroll
    for (int d = 0; d < 4; ++d)
      accI[d] = __builtin_amdgcn_mfma_i32_16x16x64_i8(aI[d], bI[tap], accI[d], 0, 0, 0);
    aC1 = __builtin_amdgcn_mfma_f32_16x16x32_bf16(aW0, bX[tap][0], aC1, 0, 0, 0);
    aC1 = __builtin_amdgcn_mfma_f32_16x16x32_bf16(aW1, bX[tap][1], aC1, 0, 0, 0);
  }

  // ---- epilogue (proven f64 path): C/D col(n=px)=l16, row(m=oc)=quad*4+r ----
  const int w = nt * 16 + l16;
#pragma unroll
  for (int r = 0; r < 4; ++r) {
    const int ocr = octile * 16 + quad * 4 + r;
    double a0 = (((double)accI[3][r] * 256.0 + (double)accI[2][r]) * 256.0 +
                 (double)accI[1][r]) * 256.0 + (double)accI[0][r];
    a0 = a0 * (1.0 / 2147483648.0) + (double)bias[ocr];
    double p0d = 1.0 / (1.0 + exp(-a0));
    const int o = ((b * 64 + ocr) * 32 + h) * 32 + w;
    float su = threefry_u((uint32_t)o);
    float nx = ((double)su < p0d) ? 1.0f : -1.0f;
    float p0 = (float)p0d;
    float s1 = p0 * (1.0f - p0);
    float dq = 2.0f * nx * s1 * aC1[r];
    out[o] = nx;
    out[262144 + o] = dq;
  }
}

extern "C" void kernel_launch(void* const* d_in, const int* in_sizes, int n_in,
                              void* d_out, int out_size, void* d_ws, size_t ws_size,
                              hipStream_t stream) {
  const float* x      = (const float*)d_in[0];
  const float* q      = (const float*)d_in[1];
  const float* weight = (const float*)d_in[2];
  const float* bias   = (const float*)d_in[3];
  float* out = (float*)d_out;
  char* ws   = (char*)d_ws;

  // prep: 128 row blocks + 4 border blocks + 144 weight blocks = 276
  prep_kernel<<<276, 256, 0, stream>>>(x, q, weight, ws);
  // main: (b*32+h)*2+nt = 256 blocks, 4 waves each (oc-tiles)
  main_kernel<<<256, 256, 0, stream>>>(ws, bias, out);
}

// Round 11
// 69.972 us; speedup vs baseline: 1.9235x; 1.0169x over previous
//
#include <hip/hip_runtime.h>
#include <cstdint>

// Problem: B=4, IC=OC=64, H=W=32, K=3, PAD=1
// Outputs: new_x (262144 f32), new_q (262144 f32) concatenated.
//
//   a0 = conv3x3(x,W,pad=1)+bias ; p0 = sigmoid(a0)
//   new_x = 2*(u < p0) - 1,  u = JAX threefry2x32-20, key=(0,42),
//           partitionable counter mode, draw = out0^out1   [verified r2]
//   new_q = 2*new_x*s1*C1   [1st-order Taylor; residual ~1.2e-4 << 2e-2, r7]
//     s1 = p0(1-p0),  C1 = conv3x3(x*q, W)
//
// Round 11: kill the image-plane ws round-trip. K1 digitizes weights only
// (the one truly global table). K2 (main) transposes its own 3-row halo into
// LDS (r8 phase-2a, proven correct; r8's regression was grid.sync, absent
// here) and runs the r10 MFMA loop with B-frags from LDS. All values and
// accumulation order bit-identical to r10 -> absmax must stay 1.182556e-4.
// a0 path EXACT (r2-r10): W as 4 signed radix-256 digits of round(W*2^31),
// x as i8, mfma_i32_16x16x64_i8 (i32 exact), f64 reconstruction + f64 exp.
// Fragment layouts (16x16 family): A[m=lane&15][k=quad*(K/4)+j],
// B[k=quad*(K/4)+j][n=lane&15], C/D col(n)=lane&15, row(m)=quad*4+reg.

typedef __attribute__((ext_vector_type(4))) int   i32x4;
typedef __attribute__((ext_vector_type(8))) short s16x8;
typedef __attribute__((ext_vector_type(4))) float f32x4;

// ---- ws byte offsets (weights only now) ----
static constexpr int OFF_WD = 0;        // i8  [dig4][tap9][oc64][ic64] 147,456 B
static constexpr int OFF_WB = 147456;   // bf16[tap9][oc64][ic64]        73,728 B
// total ws use: 221,184 B

// LDS strides (per pixel), padded
static constexpr int X8_STRIDE = 80;    // bytes  (64 + 16 pad)
static constexpr int XQ_STRIDE = 72;    // ushorts (64 + 8 pad = 144 B)

__device__ __forceinline__ uint32_t rotl32(uint32_t v, int n) {
  return (v << n) | (v >> (32 - n));
}

__device__ __forceinline__ unsigned short f2bf(float f) {
  uint32_t u = __float_as_uint(f);
  uint32_t r = (u + 0x7FFFu + ((u >> 16) & 1u)) >> 16;   // RNE
  return (unsigned short)r;
}

// JAX threefry2x32-20, key=(0,42), partitionable: counter (0,j), draw=out0^out1
__device__ __forceinline__ float threefry_u(uint32_t j) {
  uint32_t x0 = 0u, x1 = j;
  const uint32_t ks1 = 42u, ks2 = 0x1BD11BDAu ^ 42u;
  x0 += 0u; x1 += ks1;
#define QR(rot) { x0 += x1; x1 = rotl32(x1, rot); x1 ^= x0; }
  QR(13) QR(15) QR(26) QR(6)
  x0 += ks1; x1 += ks2 + 1u;
  QR(17) QR(29) QR(16) QR(24)
  x0 += ks2; x1 += 0u + 2u;
  QR(13) QR(15) QR(26) QR(6)
  x0 += 0u; x1 += ks1 + 3u;
  QR(17) QR(29) QR(16) QR(24)
  x0 += ks1; x1 += ks2 + 4u;
  QR(13) QR(15) QR(26) QR(6)
  x0 += ks2; x1 += 0u + 5u;
#undef QR
  uint32_t bits = x0 ^ x1;
  return __uint_as_float((bits >> 9) | 0x3F800000u) - 1.0f;
}

// ---------------- K1: weight digitization only (144 blocks x 256) -------------------
__global__ __launch_bounds__(256) void wprep_kernel(
    const float* __restrict__ weight, char* __restrict__ ws) {
  int k  = blockIdx.x * 256 + threadIdx.x;   // < 36864, k = tap*4096 + oc*64 + ic
  int ic = k & 63;
  int t  = k >> 6;
  int oc  = t & 63;
  int tap = t >> 6;
  int kh = tap / 3, kw = tap % 3;
  float Wv = weight[((oc * 64 + ic) * 3 + kh) * 3 + kw];
  long long wi = llrint((double)Wv * 2147483648.0);   // round(W*2^31), |wi|<2^28
  char* wd = ws + OFF_WD;
#pragma unroll
  for (int dig = 0; dig < 4; ++dig) {
    signed char d = (signed char)(wi & 0xFF);          // balanced low byte
    wd[dig * 36864 + k] = d;
    wi = (wi - (long long)d) >> 8;
  }
  ((unsigned short*)(ws + OFF_WB))[k] = f2bf(Wv);
}

// ---------------- K2: halo->LDS transpose + MFMA + f64 epilogue ---------------------
// grid 256 = (b*32 + h)*2 + nt ; block 256 = 4 waves, wave = oc-tile (16 oc)
__global__ __launch_bounds__(256, 1) void main_kernel(
    const float* __restrict__ x, const float* __restrict__ q,
    const char* __restrict__ ws, const float* __restrict__ bias,
    float* __restrict__ out) {
  const char* wd           = ws + OFF_WD;
  const unsigned short* wb = (const unsigned short*)(ws + OFF_WB);

  __shared__ __align__(16) char           x8s[3 * 34 * X8_STRIDE];   // 8,160 B
  __shared__ __align__(16) unsigned short xqs[3 * 34 * XQ_STRIDE];   // 14,688 B

  const int b  = blockIdx.x >> 6;
  const int h  = (blockIdx.x >> 1) & 31;
  const int nt = blockIdx.x & 1;
  const int tid = threadIdx.x;

  // ---- zero LDS (covers borders + padding) ----
  {
    int* z1 = (int*)x8s;
#pragma unroll
    for (int i = tid; i < 3 * 34 * X8_STRIDE / 4; i += 256) z1[i] = 0;
    int* z2 = (int*)xqs;
#pragma unroll
    for (int i = tid; i < 3 * 34 * XQ_STRIDE / 2; i += 256) z2[i] = 0;
  }
  __syncthreads();

  // ---- halo transpose: 3 rows, coalesced r5-style (4 threads per ic-row) ----
  {
    const int ic = tid >> 2;
    const int w0 = (tid & 3) * 8;
#pragma unroll
    for (int r = 0; r < 3; ++r) {
      const int hg = h - 1 + r;
      if (hg >= 0 && hg < 32) {
        const int src = ((b * 64 + ic) * 32 + hg) * 32 + w0;
        float4 xa = *(const float4*)(x + src);
        float4 xb = *(const float4*)(x + src + 4);
        float4 qa = *(const float4*)(q + src);
        float4 qb = *(const float4*)(q + src + 4);
        float xv[8] = {xa.x, xa.y, xa.z, xa.w, xb.x, xb.y, xb.z, xb.w};
        float qv[8] = {qa.x, qa.y, qa.z, qa.w, qb.x, qb.y, qb.z, qb.w};
#pragma unroll
        for (int j = 0; j < 8; ++j) {
          const int wp = w0 + j + 1;   // interior 1..32
          x8s[(r * 34 + wp) * X8_STRIDE + ic] = (char)(int)xv[j];
          xqs[(r * 34 + wp) * XQ_STRIDE + ic] = f2bf(xv[j] * qv[j]);
        }
      }
    }
  }
  __syncthreads();

  const int octile = tid >> 6;
  const int lane   = tid & 63;
  const int quad   = lane >> 4;
  const int l16    = lane & 15;

  // ---- preload all 9 B-fragment sets from LDS ----
  const int pxbase = nt * 16 + l16;
  i32x4 bI[9];
  s16x8 bX[9][2];
#pragma unroll
  for (int kh = 0; kh < 3; ++kh) {
#pragma unroll
    for (int kw = 0; kw < 3; ++kw) {
      const int t = kh * 3 + kw;
      const int px = kh * 34 + pxbase + kw;
      bI[t]    = *(const i32x4*)&x8s[px * X8_STRIDE + quad * 16];
      bX[t][0] = *(const s16x8*)&xqs[px * XQ_STRIDE + quad * 8];
      bX[t][1] = *(const s16x8*)&xqs[px * XQ_STRIDE + 32 + quad * 8];
    }
  }

  i32x4 accI[4];
#pragma unroll
  for (int d = 0; d < 4; ++d) accI[d] = (i32x4){0, 0, 0, 0};
  f32x4 aC1 = {0.f, 0.f, 0.f, 0.f};

  const int aoff_i8 = (octile * 16 + l16) * 64 + quad * 16;   // bytes
  const int aoff_bf = (octile * 16 + l16) * 64 + quad * 8;    // ushort elems

#pragma unroll
  for (int tap = 0; tap < 9; ++tap) {
    i32x4 aI[4];
#pragma unroll
    for (int d = 0; d < 4; ++d)
      aI[d] = *(const i32x4*)(wd + d * 36864 + tap * 4096 + aoff_i8);
    s16x8 aW0 = *(const s16x8*)(wb + tap * 4096 + aoff_bf);
    s16x8 aW1 = *(const s16x8*)(wb + tap * 4096 + aoff_bf + 32);
#pragma unroll
    for (int d = 0; d < 4; ++d)
      accI[d] = __builtin_amdgcn_mfma_i32_16x16x64_i8(aI[d], bI[tap], accI[d], 0, 0, 0);
    aC1 = __builtin_amdgcn_mfma_f32_16x16x32_bf16(aW0, bX[tap][0], aC1, 0, 0, 0);
    aC1 = __builtin_amdgcn_mfma_f32_16x16x32_bf16(aW1, bX[tap][1], aC1, 0, 0, 0);
  }

  // ---- epilogue (proven f64 path): C/D col(n=px)=l16, row(m=oc)=quad*4+r ----
  const int w = nt * 16 + l16;
#pragma unroll
  for (int r = 0; r < 4; ++r) {
    const int ocr = octile * 16 + quad * 4 + r;
    double a0 = (((double)accI[3][r] * 256.0 + (double)accI[2][r]) * 256.0 +
                 (double)accI[1][r]) * 256.0 + (double)accI[0][r];
    a0 = a0 * (1.0 / 2147483648.0) + (double)bias[ocr];
    double p0d = 1.0 / (1.0 + exp(-a0));
    const int o = ((b * 64 + ocr) * 32 + h) * 32 + w;
    float su = threefry_u((uint32_t)o);
    float nx = ((double)su < p0d) ? 1.0f : -1.0f;
    float p0 = (float)p0d;
    float s1 = p0 * (1.0f - p0);
    float dq = 2.0f * nx * s1 * aC1[r];
    out[o] = nx;
    out[262144 + o] = dq;
  }
}

extern "C" void kernel_launch(void* const* d_in, const int* in_sizes, int n_in,
                              void* d_out, int out_size, void* d_ws, size_t ws_size,
                              hipStream_t stream) {
  const float* x      = (const float*)d_in[0];
  const float* q      = (const float*)d_in[1];
  const float* weight = (const float*)d_in[2];
  const float* bias   = (const float*)d_in[3];
  float* out = (float*)d_out;
  char* ws   = (char*)d_ws;

  // K1: weights only — 36864 items = 144 blocks x 256
  wprep_kernel<<<144, 256, 0, stream>>>(weight, ws);
  // K2: 256 blocks x 256; halo transpose in-kernel, B from LDS
  main_kernel<<<256, 256, 0, stream>>>(x, q, ws, bias, out);
}